// Round 2
// baseline (367.066 us; speedup 1.0000x reference)
//
#include <hip/hip_runtime.h>

// Median filter (k=22, REFLECT) + blend, NHWC (2,224,224,3) fp32.
// Thread-parallel exact selection: each thread owns 2 horizontally-adjacent
// pixels; the 22x22 window is re-scanned from an LDS tile per binary-search
// iteration. Two 2-float-shifted LDS copies make every thread's 24-float row
// read 16B-aligned (6x ds_read_b128). Selection = 5-threshold ladder scan
// (uniform-data prior) + bisection count scans + value-snapping scans with
// exact termination (#(v<t)==RANK -> med = max{v<t}; duplicate-safe).

#define HH 224
#define WW 224
#define CHN 3
#define KK 22
#define PT 10
#define AREA (KK * KK)   // 484
#define RANK 242         // median = 242nd smallest (1-indexed)

#define TILE 16
#define SROWS 37         // 16 + 21 staged rows
#define SCOLS 38         // 16 + 21 + 1 staged cols (extra col: aligned-read overhang)
#define RSTRIDE 40
#define COPYOFF (SROWS * RSTRIDE)   // second (shifted) copy offset

__device__ __forceinline__ int reflect224(int g) {
    int a = abs(g);
    return min(a, 2 * (HH - 1) - a);
}

__device__ __forceinline__ void load_row(const float* rp, float v[24]) {
    const float4* p = reinterpret_cast<const float4*>(rp);
#pragma unroll
    for (int q = 0; q < 6; ++q)
        *reinterpret_cast<float4*>(&v[4 * q]) = p[q];
}

// c = #(window < t) for both pixels (windows are cols [0,22) and [1,23))
__device__ __forceinline__ void count_scan2(const float* wbase, float t0, float t1,
                                            int& c0, int& c1) {
    int a0 = 0, a1 = 0;
#pragma unroll 2
    for (int r = 0; r < KK; ++r) {
        float v[24];
        load_row(wbase + r * RSTRIDE, v);
#pragma unroll
        for (int j = 0; j < 22; ++j) a0 += (v[j] < t0);
#pragma unroll
        for (int j = 0; j < 22; ++j) a1 += (v[j + 1] < t1);
    }
    c0 = a0; c1 = a1;
}

// count + M=max{v<t} + m2=min{v>=t} for both pixels
__device__ __forceinline__ void full_scan2(const float* wbase, float t0, float t1,
                                           int& c0, int& c1, float& M0o, float& M1o,
                                           float& m0o, float& m1o) {
    int a0 = 0, a1 = 0;
    float M0 = -1e30f, M1 = -1e30f, m0 = 1e30f, m1 = 1e30f;
#pragma unroll 2
    for (int r = 0; r < KK; ++r) {
        float v[24];
        load_row(wbase + r * RSTRIDE, v);
#pragma unroll
        for (int j = 0; j < 22; ++j) {
            bool lt = v[j] < t0;
            a0 += lt;
            float mx = fmaxf(M0, v[j]);
            float mn = fminf(m0, v[j]);
            M0 = lt ? mx : M0;
            m0 = lt ? m0 : mn;
        }
#pragma unroll
        for (int j = 0; j < 22; ++j) {
            bool lt = v[j + 1] < t1;
            a1 += lt;
            float mx = fmaxf(M1, v[j + 1]);
            float mn = fminf(m1, v[j + 1]);
            M1 = lt ? mx : M1;
            m1 = lt ? m1 : mn;
        }
    }
    c0 = a0; c1 = a1; M0o = M0; M1o = M1; m0o = m0; m1o = m1;
}

__global__ __launch_bounds__(128)
void median_blend_kernel(const float* __restrict__ in,
                         const float* __restrict__ blend,
                         float* __restrict__ out) {
    __shared__ __align__(16) float ls[2 * COPYOFF];

    const int tid = threadIdx.x;
    const int z  = blockIdx.z;
    const int b  = z / CHN;
    const int ch = z - b * CHN;
    const int tx0 = blockIdx.x * TILE;
    const int ty0 = blockIdx.y * TILE;

    const float f = blend[0];

    // ---- stage 37x38 reflected tile into two shifted LDS copies ----
    for (int i = tid; i < SROWS * SCOLS; i += 128) {
        int r = i / SCOLS;
        int c = i - r * SCOLS;
        int gy = reflect224(ty0 - PT + r);
        int gx = reflect224(tx0 - PT + c);
        float val = in[((b * HH + gy) * WW + gx) * CHN + ch];
        ls[r * RSTRIDE + c] = val;
        ls[COPYOFF + r * RSTRIDE + c + 2] = val;
    }
    __syncthreads();

    const int tx  = tid & 7;     // 8 groups of 2 px -> 16 wide
    const int ty  = tid >> 3;    // 16 rows
    const int x0l = tx * 2;      // 0..14, even
    // pick copy so the 24-float row read is 16B-aligned
    const int baseCol = x0l + ((x0l & 2) ? (COPYOFF + 2) : 0);
    const float* wbase = ls + ty * RSTRIDE + baseCol;

    // center values (window offset +10,+10)
    const float xc0 = ls[(ty + PT) * RSTRIDE + x0l + PT];
    const float xc1 = ls[(ty + PT) * RSTRIDE + x0l + PT + 1];

    // ---- phase 0: fixed 5-threshold ladder (uniform-data prior) ----
    float lo0 = -1e30f, hi0 = 1e30f, lo1 = -1e30f, hi1 = 1e30f;
    int clo0 = 0, chi0 = AREA, clo1 = 0, chi1 = AREA;
    {
        const float T0 = 0.40f, T1 = 0.45f, T2 = 0.50f, T3 = 0.55f, T4 = 0.60f;
        int L0[5] = {0, 0, 0, 0, 0}, L1[5] = {0, 0, 0, 0, 0};
        const float T[5] = {T0, T1, T2, T3, T4};
        for (int r = 0; r < KK; ++r) {
            float v[24];
            load_row(wbase + r * RSTRIDE, v);
#pragma unroll
            for (int k = 0; k < 5; ++k) {
#pragma unroll
                for (int j = 0; j < 22; ++j) L0[k] += (v[j] < T[k]);
#pragma unroll
                for (int j = 0; j < 22; ++j) L1[k] += (v[j + 1] < T[k]);
            }
        }
#pragma unroll
        for (int k = 0; k < 5; ++k) {      // largest T with count <= RANK-1
            if (L0[k] <= RANK - 1) { lo0 = T[k]; clo0 = L0[k]; }
            if (L1[k] <= RANK - 1) { lo1 = T[k]; clo1 = L1[k]; }
        }
#pragma unroll
        for (int k = 4; k >= 0; --k) {     // smallest T with count >= RANK
            if (L0[k] >= RANK) { hi0 = T[k]; chi0 = L0[k]; }
            if (L1[k] >= RANK) { hi1 = T[k]; chi1 = L1[k]; }
        }
    }

    // ---- phase 1: bisection count scans until bracket holds <= 3 values ----
    for (int it = 0; it < 8; ++it) {
        bool need0 = (chi0 - clo0) > 3;
        bool need1 = (chi1 - clo1) > 3;
        if (!__any(need0 || need1)) break;
        float t0 = 0.5f * (lo0 + hi0);
        float t1 = 0.5f * (lo1 + hi1);
        int c0, c1;
        count_scan2(wbase, t0, t1, c0, c1);
        if (need0) {
            if (c0 >= RANK) { hi0 = t0; chi0 = c0; }
            else            { lo0 = t0; clo0 = c0; }
        }
        if (need1) {
            if (c1 >= RANK) { hi1 = t1; chi1 = c1; }
            else            { lo1 = t1; clo1 = c1; }
        }
    }

    // ---- phase 2: value-snapping scans, exact termination ----
    float med0 = 0.0f, med1 = 0.0f;
    bool done0 = false, done1 = false;
    for (int it = 0; it < 48; ++it) {
        if (!__any(!done0 || !done1)) break;
        float t0 = 0.5f * (lo0 + hi0);
        float t1 = 0.5f * (lo1 + hi1);
        bool bad0 = !(t0 > lo0 && t0 < hi0);   // bracket degenerate -> {lo}
        bool bad1 = !(t1 > lo1 && t1 < hi1);
        int c0, c1; float M0, M1, m0, m1;
        full_scan2(wbase, t0, t1, c0, c1, M0, M1, m0, m1);
        if (!done0) {
            if (bad0)            { med0 = lo0; done0 = true; }
            else if (c0 == RANK) { med0 = M0;  done0 = true; }  // max of 242 smallest
            else if (c0 > RANK)  { hi0 = __int_as_float(__float_as_int(M0) + 1); }
            else                 { lo0 = m0; clo0 = c0; }       // snap to data value
        }
        if (!done1) {
            if (bad1)            { med1 = lo1; done1 = true; }
            else if (c1 == RANK) { med1 = M1;  done1 = true; }
            else if (c1 > RANK)  { hi1 = __int_as_float(__float_as_int(M1) + 1); }
            else                 { lo1 = m1; clo1 = c1; }
        }
    }
    if (!done0) med0 = lo0;   // unreachable safety
    if (!done1) med1 = lo1;

    // ---- blend + store ----
    const int y = ty0 + ty;
    const int x = tx0 + x0l;
    out[((b * HH + y) * WW + x) * CHN + ch]       = med0 + f * (xc0 - med0);
    out[((b * HH + y) * WW + x + 1) * CHN + ch]   = med1 + f * (xc1 - med1);
}

extern "C" void kernel_launch(void* const* d_in, const int* in_sizes, int n_in,
                              void* d_out, int out_size, void* d_ws, size_t ws_size,
                              hipStream_t stream) {
    const float* in    = (const float*)d_in[0];
    const float* blend = (const float*)d_in[1];
    float* out = (float*)d_out;

    dim3 grid(WW / TILE, HH / TILE, 2 * CHN);   // 14 x 14 x 6
    median_blend_kernel<<<grid, 128, 0, stream>>>(in, blend, out);
}

// Round 3
// 248.908 us; speedup vs baseline: 1.4747x; 1.4747x over previous
//
#include <hip/hip_runtime.h>

// Median filter (k=22, REFLECT) + blend, NHWC (2,224,224,3) fp32.
// One 64-lane wave per GROUP of 8 consecutive-x pixels (same b,c,y).
// Window (484 elems) lives in 8 regs/lane. Exact rank-242 selection via
// wave-uniform INTERPOLATION search on value (ballot+popcount counting,
// uniform-data prior), terminating exactly at cnt==RANK (median = max{v<t});
// duplicate/slow cases fall back to min-extraction. Per-wave amortization:
// slot->offset VGPRs (incl. vertical reflect) computed once, reused by all
// 8 pixels; interior-x loads are saddr+voffset only.

#define HH 224
#define WW 224
#define CHN 3
#define KK 22
#define PT 10            // pad top/left; pad bottom/right = 11
#define AREA (KK * KK)   // 484
#define RANK 242         // median = 242nd smallest (1-indexed)
#define PXW 8            // pixels per wave (x-run)
#define XGS (WW / PXW)   // 28

__device__ __forceinline__ int reflect224(int g) {
    int a = abs(g);
    return min(a, 2 * (HH - 1) - a);
}

__global__ __launch_bounds__(256)
void median_blend_kernel(const float* __restrict__ in,
                         const float* __restrict__ blend,
                         float* __restrict__ out) {
    const int lane = threadIdx.x & 63;
    const int wid  = threadIdx.x >> 6;
    const int wg = blockIdx.x * 4 + wid;        // wave-uniform group id
    // wg = ((b*CHN + c)*HH + y)*XGS + xg
    const int xg = wg % XGS;
    const int t1 = wg / XGS;
    const int y  = t1 % HH;
    const int t2 = t1 / HH;
    const int c  = t2 % CHN;
    const int b  = t2 / CHN;

    const float f = blend[0];
    const float* img  = in  + (size_t)b * (HH * WW * CHN) + c;  // idx: y*672 + x*3
    float*       outp = out + (size_t)b * (HH * WW * CHN) + c;

    const float INF = __int_as_float(0x7f800000);

    // ---- per-wave lane constants (vertical reflect absorbed) ----
    int voff[8];    // gy*672 + col*3  (x-independent part of the gather offset)
    int gy672[8];
    int colv[8];
#pragma unroll
    for (int i = 0; i < 8; ++i) {
        int s  = i * 64 + lane;
        int se = min(s, AREA - 1);
        int row = se / KK;
        int col = se - row * KK;
        int gy = reflect224(y - PT + row);
        gy672[i] = gy * (WW * CHN);
        colv[i]  = col;
        voff[i]  = gy672[i] + col * CHN;
    }

    const int x0 = xg * PXW;

    for (int j = 0; j < PXW; ++j) {
        const int x = x0 + j;

        // ---- gather the 22x22 window: 8 values per lane ----
        float v[8];
        if (x >= PT && x <= WW - 1 - (KK - 1 - PT)) {     // x in [10,212]: interior
            const float* base = img + (x - PT) * CHN;     // wave-uniform (SGPR)
#pragma unroll
            for (int i = 0; i < 8; ++i) v[i] = base[voff[i]];
        } else {
#pragma unroll
            for (int i = 0; i < 8; ++i) {
                int gx = reflect224(x - PT + colv[i]);
                v[i] = img[gy672[i] + gx * CHN];
            }
        }
        // slots >= 484 (reg 7, lanes >= 36) -> +INF sentinel
        v[7] = (lane < AREA - 448) ? v[7] : INF;

        // ---- phase A: interpolation search, exact termination ----
        float lo = 0.0f, hi = 1.0f;
        int clo = 0, chi = AREA;
        float med = 0.0f;
        bool found = false;
        float t = 0.5f;
        for (int it = 0; it < 10; ++it) {
            int cnt = 0;
#pragma unroll
            for (int i = 0; i < 8; ++i)
                cnt += __popcll(__ballot(v[i] < t));
            if (cnt == RANK) {
                float M = -INF;
#pragma unroll
                for (int i = 0; i < 8; ++i)
                    M = fmaxf(M, (v[i] < t) ? v[i] : -INF);
#pragma unroll
                for (int off = 32; off > 0; off >>= 1)
                    M = fmaxf(M, __shfl_xor(M, off, 64));
                med = M;                 // max of the 242 smallest
                found = true;
                break;
            }
            if (cnt > RANK) { hi = t; chi = cnt; }
            else            { lo = t; clo = cnt; }
            float tn = lo + (hi - lo) * (float)(RANK - clo) *
                       __builtin_amdgcn_rcpf((float)(chi - clo));
            if (!(tn > lo && tn < hi)) {
                tn = 0.5f * (lo + hi);
                if (!(tn > lo && tn < hi)) break;   // bracket exhausted (dups)
            }
            t = tn;
        }

        // ---- phase B: duplicate-safe min-extraction on the bracket ----
        if (!found) {
            int r = RANK - clo;                      // >= 1
            float w[8];
#pragma unroll
            for (int i = 0; i < 8; ++i)
                w[i] = (v[i] >= lo && v[i] < hi) ? v[i] : INF;
            for (int iter = 0; iter < AREA; ++iter) {
                float m = fminf(fminf(fminf(w[0], w[1]), fminf(w[2], w[3])),
                                fminf(fminf(w[4], w[5]), fminf(w[6], w[7])));
#pragma unroll
                for (int off = 32; off > 0; off >>= 1)
                    m = fminf(m, __shfl_xor(m, off, 64));
                int ceq = 0;
#pragma unroll
                for (int i = 0; i < 8; ++i)
                    ceq += __popcll(__ballot(w[i] == m));
                if (r <= ceq) { med = m; break; }
                r -= ceq;
#pragma unroll
                for (int i = 0; i < 8; ++i)
                    w[i] = (w[i] == m) ? INF : w[i];
            }
        }

        // ---- blend + store ----
        const float xc = img[y * (WW * CHN) + x * CHN];   // wave-uniform load
        if (lane == 0)
            outp[y * (WW * CHN) + x * CHN] = med + f * (xc - med);
    }
}

extern "C" void kernel_launch(void* const* d_in, const int* in_sizes, int n_in,
                              void* d_out, int out_size, void* d_ws, size_t ws_size,
                              hipStream_t stream) {
    const float* in    = (const float*)d_in[0];
    const float* blend = (const float*)d_in[1];
    float* out = (float*)d_out;

    const int nwaves  = 2 * CHN * HH * XGS;   // 37632
    const int nblocks = nwaves / 4;           // 9408
    median_blend_kernel<<<nblocks, 256, 0, stream>>>(in, blend, out);
}

// Round 5
// 163.591 us; speedup vs baseline: 2.2438x; 1.5215x over previous
//
#include <hip/hip_runtime.h>

// Median filter (k=22, REFLECT) + blend, NHWC (2,224,224,3) fp32.
// One wave per 8 consecutive-x pixels. Window (484) in 8 regs/lane, ballot
// counting. Warm-started interpolation search (prev pixel's median seeds the
// first probe) + bounded rank-offset extraction (peel |d|+1 maxima/minima,
// duplicate-aware) -> exact for any input incl. REFLECT duplicates.
// All cross-lane ops via proven __shfl_xor / __ballot; no uninitialized
// register reads (R4's two UB hazards removed).

#define HH 224
#define WW 224
#define CHN 3
#define KK 22
#define PT 10            // pad top/left; bottom/right = 11
#define AREA (KK * KK)   // 484
#define RANK 242         // median = 242nd smallest (1-indexed)
#define PXW 8
#define XGS (WW / PXW)   // 28
#define DT 2             // stop probing when |count-RANK| <= DT

#define INFF  __int_as_float(0x7f800000)
#define NINFF __int_as_float(0xff800000)

__device__ __forceinline__ int reflect224(int g) {
    int a = abs(g);
    return min(a, 2 * (HH - 1) - a);
}

__device__ __forceinline__ int count8(const float v[8], float t) {
    int c = 0;
#pragma unroll
    for (int i = 0; i < 8; ++i)
        c += __popcll(__ballot(v[i] < t));
    return c;
}

__device__ __forceinline__ float wave_max(float x) {
#pragma unroll
    for (int off = 32; off > 0; off >>= 1)
        x = fmaxf(x, __shfl_xor(x, off, 64));
    return x;
}

__device__ __forceinline__ float wave_min(float x) {
#pragma unroll
    for (int off = 32; off > 0; off >>= 1)
        x = fminf(x, __shfl_xor(x, off, 64));
    return x;
}

__device__ __forceinline__ void gather(float v[8], const float* __restrict__ img,
                                       const int voff[8], int lane, int x) {
    if (x >= PT && x <= WW - 1 - (KK - 1 - PT)) {      // interior: x in [10,212]
        const float* base = img + (x - PT) * CHN;      // wave-uniform base
#pragma unroll
        for (int i = 0; i < 8; ++i) v[i] = base[voff[i]];
    } else {
#pragma unroll
        for (int i = 0; i < 8; ++i) {
            int s   = i * 64 + lane;
            int se  = min(s, AREA - 1);
            int row = se / KK;
            int col = se - row * KK;
            int gy672 = voff[i] - col * CHN;           // strip col part back off
            int gx = reflect224(x - PT + col);
            v[i] = img[gy672 + gx * CHN];
        }
    }
    v[7] = (lane < AREA - 448) ? v[7] : INFF;          // slots >= 484 -> +INF
}

// Exact rank-RANK selection given last probe (t, C = #{v < t}). Destroys v.
// e = max(d+1, -d) <= 243 always, and each peel round removes >= 1 distinct
// value, so the 300-round cap is never the exit path.
__device__ __forceinline__ float extract_med(float v[8], float t, int C) {
    int d = C - RANK;
    float med = t;                                     // provably unreachable
    if (d >= 0) {
        int e = d + 1;                                 // (d+1)-th largest of {v<t}
#pragma unroll
        for (int i = 0; i < 8; ++i) v[i] = (v[i] < t) ? v[i] : NINFF;
#pragma unroll 1
        for (int r = 0; r < 300; ++r) {
            float m = fmaxf(fmaxf(fmaxf(v[0], v[1]), fmaxf(v[2], v[3])),
                            fmaxf(fmaxf(v[4], v[5]), fmaxf(v[6], v[7])));
            float M = wave_max(m);
            int q = 0;
#pragma unroll
            for (int i = 0; i < 8; ++i)
                q += __popcll(__ballot(v[i] == M));
            if (e <= q) { med = M; break; }
            e -= q;
#pragma unroll
            for (int i = 0; i < 8; ++i)
                v[i] = (v[i] == M) ? NINFF : v[i];
        }
    } else {
        int e = -d;                                    // (-d)-th smallest of {v>=t}
#pragma unroll
        for (int i = 0; i < 8; ++i) v[i] = (v[i] >= t) ? v[i] : INFF;
#pragma unroll 1
        for (int r = 0; r < 300; ++r) {
            float m = fminf(fminf(fminf(v[0], v[1]), fminf(v[2], v[3])),
                            fminf(fminf(v[4], v[5]), fminf(v[6], v[7])));
            float M = wave_min(m);
            int q = 0;
#pragma unroll
            for (int i = 0; i < 8; ++i)
                q += __popcll(__ballot(v[i] == M));
            if (e <= q) { med = M; break; }
            e -= q;
#pragma unroll
            for (int i = 0; i < 8; ++i)
                v[i] = (v[i] == M) ? INFF : v[i];
        }
    }
    return med;
}

__global__ __launch_bounds__(256)
void median_blend_kernel(const float* __restrict__ in,
                         const float* __restrict__ blend,
                         float* __restrict__ out) {
    const int lane = threadIdx.x & 63;
    const int wid  = threadIdx.x >> 6;
    const int wg = blockIdx.x * 4 + wid;        // wave-uniform group id
    // wg = ((b*CHN + c)*HH + y)*XGS + xg
    const int xg = wg % XGS;
    const int t1 = wg / XGS;
    const int y  = t1 % HH;
    const int t2 = t1 / HH;
    const int c  = t2 % CHN;
    const int b  = t2 / CHN;

    const float f = blend[0];
    const float* img  = in  + (size_t)b * (HH * WW * CHN) + c;
    float*       outp = out + (size_t)b * (HH * WW * CHN) + c;

    // per-wave lane constants: voff = gy*672 + col*3 (vertical reflect baked in)
    int voff[8];
#pragma unroll
    for (int i = 0; i < 8; ++i) {
        int s   = i * 64 + lane;
        int se  = min(s, AREA - 1);
        int row = se / KK;
        int col = se - row * KK;
        int gy  = reflect224(y - PT + row);
        voff[i] = gy * (WW * CHN) + col * CHN;
    }

    const int x0 = xg * PXW;
    float tprev = 0.5f;

    float vA[8];
    gather(vA, img, voff, lane, x0);

    for (int j = 0; j < PXW; ++j) {
        const int x = x0 + j;

        // prefetch next window (unconditional: j==PXW-1 gathers a clamped
        // dummy column so vN is always fully initialized -> no UB)
        float vN[8];
        const int xn = (j + 1 < PXW) ? (x + 1) : x;
        gather(vN, img, voff, lane, xn);

        // ---- warm-started interpolation probes ----
        float t = tprev;
        int C = count8(vA, t);
        int d = C - RANK;
        float lo = 0.0f, hi = 1.0f;
        int clo = 0, chi = AREA;
#pragma unroll 1
        for (int it = 0; it < 16; ++it) {
            if (d >= -DT && d <= DT) break;
            if (d > 0) { hi = t; chi = C; }
            else       { lo = t; clo = C; }
            float tn = lo + (hi - lo) * (float)(RANK - clo) *
                       __builtin_amdgcn_rcpf((float)(chi - clo));
            if (!(tn > lo && tn < hi)) {
                tn = 0.5f * (lo + hi);
                if (!(tn > lo && tn < hi)) break;  // degenerate (duplicates)
            }
            t = tn;
            C = count8(vA, t);
            d = C - RANK;
        }

        // ---- exact bounded extraction (duplicate-aware) ----
        float med = extract_med(vA, t, C);
        tprev = med;                                // warm start for next pixel

        const float xc = img[y * (WW * CHN) + x * CHN];   // wave-uniform load
        if (lane == 0)
            outp[y * (WW * CHN) + x * CHN] = med + f * (xc - med);

#pragma unroll
        for (int i = 0; i < 8; ++i) vA[i] = vN[i];
    }
}

extern "C" void kernel_launch(void* const* d_in, const int* in_sizes, int n_in,
                              void* d_out, int out_size, void* d_ws, size_t ws_size,
                              hipStream_t stream) {
    const float* in    = (const float*)d_in[0];
    const float* blend = (const float*)d_in[1];
    float* out = (float*)d_out;

    const int nwaves  = 2 * CHN * HH * XGS;   // 37632
    const int nblocks = nwaves / 4;           // 9408
    median_blend_kernel<<<nblocks, 256, 0, stream>>>(in, blend, out);
}

// Round 6
// 162.880 us; speedup vs baseline: 2.2536x; 1.0044x over previous
//
#include <hip/hip_runtime.h>

// Median filter (k=22, REFLECT) + blend, NHWC (2,224,224,3) fp32.
// One wave per 8 consecutive-x pixels, processed as 4 PAIRS in lockstep.
// Window (484) in 8 regs/lane per pixel, ballot counting. Warm-started
// interpolation search with per-pixel sticky flags (shared loop overhead),
// then pair-interleaved bounded rank-offset extraction: sign-folded max-peel
// (bottom-side peel == top-side peel on -v) so A/B share one code path and
// their shuffle-reduce chains overlap. Exact for any input incl. REFLECT
// duplicates; no uninitialized reads; proven __shfl_xor/__ballot cross-lane.

#define HH 224
#define WW 224
#define CHN 3
#define KK 22
#define PT 10            // pad top/left; bottom/right = 11
#define AREA (KK * KK)   // 484
#define RANK 242         // median = 242nd smallest (1-indexed)
#define PXW 8
#define XGS (WW / PXW)   // 28
#define DT 2             // stop probing when |count-RANK| <= DT

#define INFF  __int_as_float(0x7f800000)
#define NINFF __int_as_float(0xff800000)

__device__ __forceinline__ int reflect224(int g) {
    int a = abs(g);
    return min(a, 2 * (HH - 1) - a);
}

__device__ __forceinline__ int count8(const float v[8], float t) {
    int c = 0;
#pragma unroll
    for (int i = 0; i < 8; ++i)
        c += __popcll(__ballot(v[i] < t));
    return c;
}

__device__ __forceinline__ void gather(float v[8], const float* __restrict__ img,
                                       const int voff[8], int lane, int x) {
    if (x >= PT && x <= WW - 1 - (KK - 1 - PT)) {      // interior: x in [10,212]
        const float* base = img + (x - PT) * CHN;      // wave-uniform base
#pragma unroll
        for (int i = 0; i < 8; ++i) v[i] = base[voff[i]];
    } else {
#pragma unroll
        for (int i = 0; i < 8; ++i) {
            int s   = i * 64 + lane;
            int se  = min(s, AREA - 1);
            int row = se / KK;
            int col = se - row * KK;
            int gy672 = voff[i] - col * CHN;
            int gx = reflect224(x - PT + col);
            v[i] = img[gy672 + gx * CHN];
        }
    }
    v[7] = (lane < AREA - 448) ? v[7] : INFF;          // slots >= 484 -> +INF
}

__global__ __launch_bounds__(256)
void median_blend_kernel(const float* __restrict__ in,
                         const float* __restrict__ blend,
                         float* __restrict__ out) {
    const int lane = threadIdx.x & 63;
    const int wid  = threadIdx.x >> 6;
    const int wg = blockIdx.x * 4 + wid;        // wave-uniform group id
    // wg = ((b*CHN + c)*HH + y)*XGS + xg
    const int xg = wg % XGS;
    const int t1 = wg / XGS;
    const int y  = t1 % HH;
    const int t2 = t1 / HH;
    const int c  = t2 % CHN;
    const int b  = t2 / CHN;

    const float f = blend[0];
    const float* img  = in  + (size_t)b * (HH * WW * CHN) + c;
    float*       outp = out + (size_t)b * (HH * WW * CHN) + c;

    // per-wave lane constants: voff = gy*672 + col*3 (vertical reflect baked in)
    int voff[8];
#pragma unroll
    for (int i = 0; i < 8; ++i) {
        int s   = i * 64 + lane;
        int se  = min(s, AREA - 1);
        int row = se / KK;
        int col = se - row * KK;
        int gy  = reflect224(y - PT + row);
        voff[i] = gy * (WW * CHN) + col * CHN;
    }

    const int x0 = xg * PXW;
    float tprev = 0.5f;

#pragma unroll 1
    for (int j = 0; j < PXW; j += 2) {
        const int xA = x0 + j;
        const int xB = xA + 1;

        float vA[8], vB[8];
        gather(vA, img, voff, lane, xA);
        gather(vB, img, voff, lane, xB);

        // ---- warm-started interpolation probes, pair in lockstep ----
        float tA = tprev, tB = tprev;
        int CA = count8(vA, tA);
        int CB = count8(vB, tB);
        float loA = 0.0f, hiA = 1.0f, loB = 0.0f, hiB = 1.0f;
        int cloA = 0, chiA = AREA, cloB = 0, chiB = AREA;
        bool actA = true, actB = true;
#pragma unroll 1
        for (int it = 0; it < 16 && (actA || actB); ++it) {
            if (actA) {
                int d = CA - RANK;
                if (d >= -DT && d <= DT) actA = false;
                else {
                    if (d > 0) { hiA = tA; chiA = CA; }
                    else       { loA = tA; cloA = CA; }
                    float tn = loA + (hiA - loA) * (float)(RANK - cloA) *
                               __builtin_amdgcn_rcpf((float)(chiA - cloA));
                    if (!(tn > loA && tn < hiA)) {
                        tn = 0.5f * (loA + hiA);
                        if (!(tn > loA && tn < hiA)) actA = false;  // degenerate
                    }
                    if (actA) { tA = tn; CA = count8(vA, tA); }
                }
            }
            if (actB) {
                int d = CB - RANK;
                if (d >= -DT && d <= DT) actB = false;
                else {
                    if (d > 0) { hiB = tB; chiB = CB; }
                    else       { loB = tB; cloB = CB; }
                    float tn = loB + (hiB - loB) * (float)(RANK - cloB) *
                               __builtin_amdgcn_rcpf((float)(chiB - cloB));
                    if (!(tn > loB && tn < hiB)) {
                        tn = 0.5f * (loB + hiB);
                        if (!(tn > loB && tn < hiB)) actB = false;  // degenerate
                    }
                    if (actB) { tB = tn; CB = count8(vB, tB); }
                }
            }
        }

        // ---- pair-interleaved bounded extraction (sign-folded max-peel) ----
        // top side (d>=0): need (d+1)-th largest of {v<t}    -> peel max of v
        // bottom side    : need (-d)-th smallest of {v>=t}   -> peel max of -v
        const int dA = CA - RANK, dB = CB - RANK;
        const bool topA = (dA >= 0), topB = (dB >= 0);
        int eA = topA ? dA + 1 : -dA;
        int eB = topB ? dB + 1 : -dB;
        const int sgnA = topA ? 0 : 0x80000000;
        const int sgnB = topB ? 0 : 0x80000000;
#pragma unroll
        for (int i = 0; i < 8; ++i) {
            bool ltA = vA[i] < tA;                 // member iff lt == top
            float sA = __int_as_float(__float_as_int(vA[i]) ^ sgnA);
            vA[i] = (ltA == topA) ? sA : NINFF;
            bool ltB = vB[i] < tB;
            float sB = __int_as_float(__float_as_int(vB[i]) ^ sgnB);
            vB[i] = (ltB == topB) ? sB : NINFF;
        }
        // (sentinels +INF fold to -INF on bottom side and are masked on top;
        //  they are never selected since e <= #real candidates.)

        float medA = tA, medB = tB;                // provably overwritten
        bool doneA = false, doneB = false;
#pragma unroll 1
        for (int r = 0; r < 300 && !(doneA && doneB); ++r) {
            float mA = fmaxf(fmaxf(fmaxf(vA[0], vA[1]), fmaxf(vA[2], vA[3])),
                             fmaxf(fmaxf(vA[4], vA[5]), fmaxf(vA[6], vA[7])));
            float mB = fmaxf(fmaxf(fmaxf(vB[0], vB[1]), fmaxf(vB[2], vB[3])),
                             fmaxf(fmaxf(vB[4], vB[5]), fmaxf(vB[6], vB[7])));
#pragma unroll
            for (int off = 32; off > 0; off >>= 1) {
                mA = fmaxf(mA, __shfl_xor(mA, off, 64));
                mB = fmaxf(mB, __shfl_xor(mB, off, 64));
            }
            if (!doneA) {
                int q = 0;
#pragma unroll
                for (int i = 0; i < 8; ++i)
                    q += __popcll(__ballot(vA[i] == mA));
                if (eA <= q) {
                    medA = __int_as_float(__float_as_int(mA) ^ sgnA);
                    doneA = true;
                } else {
                    eA -= q;
#pragma unroll
                    for (int i = 0; i < 8; ++i)
                        vA[i] = (vA[i] == mA) ? NINFF : vA[i];
                }
            }
            if (!doneB) {
                int q = 0;
#pragma unroll
                for (int i = 0; i < 8; ++i)
                    q += __popcll(__ballot(vB[i] == mB));
                if (eB <= q) {
                    medB = __int_as_float(__float_as_int(mB) ^ sgnB);
                    doneB = true;
                } else {
                    eB -= q;
#pragma unroll
                    for (int i = 0; i < 8; ++i)
                        vB[i] = (vB[i] == mB) ? NINFF : vB[i];
                }
            }
        }
        tprev = medB;                              // warm start for next pair

        // ---- blend + store ----
        const float xcA = img[y * (WW * CHN) + xA * CHN];
        const float xcB = img[y * (WW * CHN) + xB * CHN];
        if (lane == 0) {
            outp[y * (WW * CHN) + xA * CHN] = medA + f * (xcA - medA);
            outp[y * (WW * CHN) + xB * CHN] = medB + f * (xcB - medB);
        }
    }
}

extern "C" void kernel_launch(void* const* d_in, const int* in_sizes, int n_in,
                              void* d_out, int out_size, void* d_ws, size_t ws_size,
                              hipStream_t stream) {
    const float* in    = (const float*)d_in[0];
    const float* blend = (const float*)d_in[1];
    float* out = (float*)d_out;

    const int nwaves  = 2 * CHN * HH * XGS;   // 37632
    const int nblocks = nwaves / 4;           // 9408
    median_blend_kernel<<<nblocks, 256, 0, stream>>>(in, blend, out);
}